// Round 17
// baseline (337.816 us; speedup 1.0000x reference)
//
#include <hip/hip_runtime.h>
#include <math.h>

typedef short  short8  __attribute__((ext_vector_type(8)));
typedef float  floatx4 __attribute__((ext_vector_type(4)));
typedef int    intx4   __attribute__((ext_vector_type(4)));

#define NROWS 16384
#define KC    2048
#define DIM   512
#define MB    32      // rows per k_main block

// quantization scales: W uniform(+-1/2048) -> sw = (1/2048)/127; x ~ N(0,1) -> sx = 1/20
#define INV_SW 260096.0f          // 1/sw = 127*2048
#define INV_SX 20.0f              // 1/sx
#define SCALE2 3.8447312e-07f     // 2*sx*sw = 0.1/260096

// d_out element offsets (all float32): loss, q[8388608], perplexity, idx[16384]
#define OUT_Q_OFF    1
#define OUT_P_OFF    (1 + 8388608)
#define OUT_IDX_OFF  (1 + 8388608 + 1)

// ws byte offsets
#define WS_COUNTS 0        // int[2048]   (zeroed in k_prep)
#define WS_LOSS   8192     // float       (zeroed in k_prep)
#define WS_W2D    8448     // double[2048]
#define WS_W2F    24832    // float[2048]
#define WS_WB     33024    // int8[2048*512] codebook, i8-FRAGMENT-ORDERED (1 MB)

__device__ __forceinline__ int q8(float v, float s) {
  int q = __float2int_rn(v * s);
  return q < -127 ? -127 : (q > 127 ? 127 : q);
}

// monotone pack: fp32 score -> ascending uint, low 11 bits replaced by code
__device__ __forceinline__ unsigned int packsc(float s, int code) {
  union { float f; unsigned int u; } v; v.f = s;
  unsigned int u = v.u;
  u = (u & 0x80000000u) ? ~u : (u | 0x80000000u);
  return (u & 0xFFFFF800u) | (unsigned int)code;
}

__device__ __forceinline__ void ins3(unsigned int* t, unsigned int v) {
  if (v < t[2]) {
    t[2] = v;
    if (t[2] < t[1]) { unsigned int tmp = t[1]; t[1] = t[2]; t[2] = tmp; }
    if (t[1] < t[0]) { unsigned int tmp = t[0]; t[0] = t[1]; t[1] = tmp; }
  }
}

// ---------------- k_prep: SINGLE-PASS (R15): 512 blocks, each handles 4 codes:
// counts/loss zeroing + ||W_k||^2 (fp64+fp32) + i8 fragment-order reorder.
__global__ __launch_bounds__(256) void k_prep(
    const float* __restrict__ W,
    double* __restrict__ w2d, float* __restrict__ w2f,
    signed char* __restrict__ Wb,
    int* __restrict__ counts, float* __restrict__ loss_acc)
{
  const int bid = blockIdx.x;
  const int tid = threadIdx.x;

  if (bid < 8) counts[bid * 256 + tid] = 0;
  if (bid == 8 && tid == 0) *loss_acc = 0.0f;

  const int wave = tid >> 6;
  const int lane = tid & 63;
  const int k = bid * 4 + wave;

  // ---- ||W_k||^2
  {
    const float4* row = (const float4*)(W + (size_t)k * DIM);
    float4 a = row[lane];
    float4 b = row[lane + 64];
    double acc = 0.0;
    acc += (double)a.x*a.x + (double)a.y*a.y + (double)a.z*a.z + (double)a.w*a.w;
    acc += (double)b.x*b.x + (double)b.y*b.y + (double)b.z*b.z + (double)b.w*b.w;
    for (int o = 32; o > 0; o >>= 1) acc += __shfl_down(acc, o);
    if (lane == 0) { w2d[k] = acc; w2f[k] = (float)acc; }
  }

  // ---- i8 reorder: lane handles dims [lane*8, lane*8+8) of code k
  {
    int d0  = lane * 8;
    int kb  = lane >> 3;           // d0 >> 6
    int q   = (lane >> 1) & 3;     // (d0 >> 4) & 3
    int l15 = k & 15, c16 = k >> 4;
    const float* sp = W + (size_t)k * DIM + d0;
    float4 a = *(const float4*)sp;
    float4 b = *(const float4*)(sp + 4);
    int b0 = (q8(a.x, INV_SW) & 255)        | ((q8(a.y, INV_SW) & 255) << 8) |
             ((q8(a.z, INV_SW) & 255) << 16) | ((q8(a.w, INV_SW) & 255) << 24);
    int b1 = (q8(b.x, INV_SW) & 255)        | ((q8(b.y, INV_SW) & 255) << 8) |
             ((q8(b.z, INV_SW) & 255) << 16) | ((q8(b.w, INV_SW) & 255) << 24);
    int2 v = make_int2(b0, b1);
    *(int2*)(Wb + (size_t)(c16 * 8 + kb) * 1024 + (q * 16 + l15) * 16 + (d0 & 15)) = v;
  }
}

// ---------------- k_main: R15 structure (105us) with ONE change: Phases D/E
// read W and x via NON-TEMPORAL loads (ext-vector floatx4 — HIP float4 is a
// struct and rejected by the builtin, R16 compile fail). Theory: D/E's random
// fp32-W reads (4MB hot footprint = full per-XCD L2) evict the 1MB Wb; Wb's
// ~50MB HBM/L3 re-fetch sets Phase B's invariant 8.3 TB/s pace. D is
// latency-tolerant (R13 null), so L3-serving D/E is free.
// Closed knobs: B scheduling (R5/R7/R9/R11), MB (R8), finale (R10), D-coop
// (R13), A-dedup (R14, kept), nt q-stores (R15: -5MB FETCH, kept).
__global__ __launch_bounds__(256, 2) void k_main(
    const float* __restrict__ x, const float* __restrict__ W,
    const signed char* __restrict__ Wb,
    const float* __restrict__ w2f, const double* __restrict__ w2d,
    int* __restrict__ counts, float* __restrict__ out,
    float* __restrict__ loss_acc)
{
  __shared__ unsigned int candU[MB * 192];   // 24 KB packed candidates
  __shared__ unsigned int ps8[MB][8][8];     // 8 KB partial top-8
  __shared__ int    top8i[MB][8];
  __shared__ double sc8[MB][8];
  __shared__ int4   idx3s[MB];
  __shared__ float  lred[4];
  __shared__ __align__(16) signed char xs[MB * 512];  // 16 KB i8 x-tile, XOR-swizzled

  const int tid  = threadIdx.x;
  const int w    = tid >> 6;          // wave id: owns codes [w*512, w*512+512)
  const int lane = tid & 63;
  const int q    = lane >> 4;
  const int l15  = lane & 15;
  const int n0   = blockIdx.x * MB;
  const int b    = n0 >> 8;
  const int t0   = n0 & 255;

  // ---- Phase A1: cooperative x quantize -> LDS (R14). Wave w covers dims
  //      [w*128, w*128+128); lane (t=lane&31, h=lane>>5) packs 64 dims for row t.
  {
    const float* xg = x + (size_t)b * DIM * 256 + t0 + (lane & 31);
    const int t  = lane & 31;
    const int gb = w * 8 + (lane >> 5) * 4;       // first granule of this lane
    #pragma unroll
    for (int c = 0; c < 4; ++c) {
      int g = gb + c;
      intx4 v;
      #pragma unroll
      for (int u = 0; u < 4; ++u) {
        int d = g * 16 + u * 4;
        int a0 = q8(xg[(size_t)(d + 0) * 256], INV_SX);
        int a1 = q8(xg[(size_t)(d + 1) * 256], INV_SX);
        int a2 = q8(xg[(size_t)(d + 2) * 256], INV_SX);
        int a3 = q8(xg[(size_t)(d + 3) * 256], INV_SX);
        v[u] = (a0 & 255) | ((a1 & 255) << 8) | ((a2 & 255) << 16) | ((a3 & 255) << 24);
      }
      *(intx4*)(xs + t * 512 + ((g ^ (t & 7)) << 4)) = v;
    }
  }
  __syncthreads();

  // ---- Phase A2: rebuild i8 A-fragments from LDS (16 ds_read_b128/lane)
  intx4 af[2][8];
  #pragma unroll
  for (int rs = 0; rs < 2; ++rs)
    #pragma unroll
    for (int kb = 0; kb < 8; ++kb) {
      int t = l15 + rs * 16;
      int g = kb * 4 + q;
      af[rs][kb] = *(const intx4*)(xs + t * 512 + ((g ^ (t & 7)) << 4));
    }

  unsigned int ts[2][4][3];   // packed top-3 per (rowset, acc-reg)
  #pragma unroll
  for (int rs = 0; rs < 2; ++rs)
    #pragma unroll
    for (int i = 0; i < 4; ++i)
      #pragma unroll
      for (int j = 0; j < 3; ++j) ts[rs][i][j] = 0xFFFFFFFFu;

  // ---- Phase B: barrier-free i8 GEMM. Each wave streams its 256 KB of
  //      fragment-ordered Wb through an 8-deep register ring.
  {
    const signed char* base = Wb + (size_t)(w * 256) * 1024 + lane * 16;
    intx4 ring[8];
    #pragma unroll
    for (int p = 0; p < 8; ++p)
      ring[p] = *(const intx4*)(base + (size_t)p * 1024);

    for (int ct = 0; ct < 32; ++ct) {
      intx4 acc0 = {0, 0, 0, 0};
      intx4 acc1 = {0, 0, 0, 0};
      #pragma unroll
      for (int kb = 0; kb < 8; ++kb) {
        int it = ct * 8 + kb;
        int nf = (it + 8 < 256) ? (it + 8) : 255;   // wave-uniform clamp
        intx4 bfr = ring[kb];
        ring[kb] = *(const intx4*)(base + (size_t)nf * 1024);
        acc0 = __builtin_amdgcn_mfma_i32_16x16x64_i8(af[0][kb], bfr, acc0, 0, 0, 0);
        acc1 = __builtin_amdgcn_mfma_i32_16x16x64_i8(af[1][kb], bfr, acc1, 0, 0, 0);
      }
      int code = (w * 32 + ct) * 16 + l15;
      float w2 = w2f[code];
      #pragma unroll
      for (int i = 0; i < 4; ++i) {
        ins3(ts[0][i], packsc(fmaf(-SCALE2, (float)acc0[i], w2), code));
        ins3(ts[1][i], packsc(fmaf(-SCALE2, (float)acc1[i], w2), code));
      }
    }
  }

  // ---- Phase C: dump packed candidates, two-stage merge -> top-8 per row
  #pragma unroll
  for (int rs = 0; rs < 2; ++rs)
    #pragma unroll
    for (int i = 0; i < 4; ++i) {
      int row = rs * 16 + q * 4 + i;
      #pragma unroll
      for (int j = 0; j < 3; ++j)
        candU[row * 192 + w * 48 + l15 * 3 + j] = ts[rs][i][j];
    }
  __syncthreads();

  {
    int row = tid >> 3, sl = tid & 7;
    unsigned int s8[8];
    #pragma unroll
    for (int k = 0; k < 8; ++k) s8[k] = 0xFFFFFFFFu;
    for (int e = 0; e < 24; ++e) {
      unsigned int v = candU[row * 192 + sl * 24 + e];
      if (v < s8[7]) {
        s8[7] = v;
        #pragma unroll
        for (int k = 7; k >= 1; --k)
          if (s8[k] < s8[k - 1]) { unsigned int t = s8[k-1]; s8[k-1] = s8[k]; s8[k] = t; }
      }
    }
    #pragma unroll
    for (int k = 0; k < 8; ++k) ps8[row][sl][k] = s8[k];
  }
  __syncthreads();

  if (tid < MB) {
    unsigned int s8[8];
    #pragma unroll
    for (int k = 0; k < 8; ++k) s8[k] = 0xFFFFFFFFu;
    const unsigned int* src = &ps8[tid][0][0];
    for (int e = 0; e < 64; ++e) {
      unsigned int v = src[e];
      if (v < s8[7]) {
        s8[7] = v;
        #pragma unroll
        for (int k = 7; k >= 1; --k)
          if (s8[k] < s8[k - 1]) { unsigned int t = s8[k-1]; s8[k-1] = s8[k]; s8[k] = t; }
      }
    }
    #pragma unroll
    for (int k = 0; k < 8; ++k) top8i[tid][k] = (int)(s8[k] & 0x7FFu);
  }
  __syncthreads();

  // ---- Phase D: cooperative exact fp64 re-score (R13 structure). W and x
  //      reads NON-TEMPORAL (floatx4/scalar): serve from L3, keep Wb in L2.
  {
    int rr = tid >> 3, j = tid & 7;
    const float* xr = x + (size_t)b * DIM * 256 + t0 + rr;
    const floatx4* wp[8];
    #pragma unroll
    for (int k = 0; k < 8; ++k)
      wp[k] = (const floatx4*)(W + (size_t)top8i[rr][k] * DIM);
    double p[8] = {0, 0, 0, 0, 0, 0, 0, 0};
    #pragma unroll 4
    for (int c4 = 0; c4 < 16; ++c4) {
      int d0 = j * 64 + c4 * 4;
      float xv0 = __builtin_nontemporal_load(xr + (size_t)(d0 + 0) * 256);
      float xv1 = __builtin_nontemporal_load(xr + (size_t)(d0 + 1) * 256);
      float xv2 = __builtin_nontemporal_load(xr + (size_t)(d0 + 2) * 256);
      float xv3 = __builtin_nontemporal_load(xr + (size_t)(d0 + 3) * 256);
      #pragma unroll
      for (int k = 0; k < 8; ++k) {
        floatx4 wv = __builtin_nontemporal_load(wp[k] + (d0 >> 2));
        double s = fma((double)xv0, (double)wv[0], fma((double)xv1, (double)wv[1],
                   fma((double)xv2, (double)wv[2], (double)xv3 * (double)wv[3])));
        p[k] += s;
      }
    }
    #pragma unroll
    for (int off = 1; off < 8; off <<= 1)
      #pragma unroll
      for (int k = 0; k < 8; ++k)
        p[k] += __shfl_xor(p[k], off);
    sc8[rr][j] = w2d[top8i[rr][j]] - 2.0 * p[j];
  }
  __syncthreads();

  // ---- final order: sort 8 by (score, index) asc == top_k(-dist) order
  if (tid < MB) {
    double sd[8]; int id_[8];
    #pragma unroll
    for (int k = 0; k < 8; ++k) { sd[k] = sc8[tid][k]; id_[k] = top8i[tid][k]; }
    #pragma unroll
    for (int i = 0; i < 7; ++i)
      #pragma unroll
      for (int jj = 0; jj < 7; ++jj)
        if (jj < 7 - i) {
          bool sw = (sd[jj] > sd[jj+1]) ||
                    (sd[jj] == sd[jj+1] && id_[jj] > id_[jj+1]);
          if (sw) {
            double td = sd[jj]; sd[jj] = sd[jj+1]; sd[jj+1] = td;
            int    tt = id_[jj]; id_[jj] = id_[jj+1]; id_[jj+1] = tt;
          }
        }
    int n = n0 + tid;
    idx3s[tid] = make_int4(id_[0], id_[1], id_[2], 0);
    out[OUT_IDX_OFF + n] = (float)id_[2];
    atomicAdd(&counts[id_[0]], 1);
    atomicAdd(&counts[id_[1]], 1);
    atomicAdd(&counts[id_[2]], 1);
  }
  __syncthreads();

  // ---- Phase E: fused quantize + straight-through + loss. W/x reads and q
  //      stores all NON-TEMPORAL (keep Wb L2-resident).
  {
    int rr = tid & 31, g = tid >> 5;       // 8 d-groups of 64 dims
    int4 ii = idx3s[rr];
    const floatx4* w0 = (const floatx4*)(W + (size_t)ii.x * DIM);
    const floatx4* w1 = (const floatx4*)(W + (size_t)ii.y * DIM);
    const floatx4* w2 = (const floatx4*)(W + (size_t)ii.z * DIM);
    const float*  xr = x + (size_t)b * DIM * 256 + t0 + rr;
    float* outq = out + OUT_Q_OFF + (size_t)b * DIM * 256 + t0 + rr;
    float lsum = 0.0f;
    #pragma unroll 4
    for (int d4 = 0; d4 < 16; ++d4) {
      int idx4 = g * 16 + d4;
      floatx4 a0 = __builtin_nontemporal_load(w0 + idx4);
      floatx4 a1 = __builtin_nontemporal_load(w1 + idx4);
      floatx4 a2 = __builtin_nontemporal_load(w2 + idx4);
      float qv[4] = { (a0[0] + a1[0] + a2[0]) * (1.0f/3.0f),
                      (a0[1] + a1[1] + a2[1]) * (1.0f/3.0f),
                      (a0[2] + a1[2] + a2[2]) * (1.0f/3.0f),
                      (a0[3] + a1[3] + a2[3]) * (1.0f/3.0f) };
      #pragma unroll
      for (int e = 0; e < 4; ++e) {
        size_t off = (size_t)(idx4 * 4 + e) * 256;
        float xv = __builtin_nontemporal_load(xr + off);
        float diff = qv[e] - xv;             // quantized - inp
        __builtin_nontemporal_store(xv + diff, outq + off);  // straight-through
        lsum += diff * diff;
      }
    }
    for (int o = 32; o > 0; o >>= 1) lsum += __shfl_down(lsum, o);
    if (lane == 0) lred[w] = lsum;
  }
  __syncthreads();
  if (tid == 0)
    atomicAdd(loss_acc, (lred[0] + lred[1]) + (lred[2] + lred[3]));
}

// ---------------- k_final: loss + perplexity
__global__ __launch_bounds__(256) void k_final(
    const int* __restrict__ counts, const float* __restrict__ loss_acc,
    float* __restrict__ out)
{
  int tid = threadIdx.x;
  float ent = 0.0f;
  for (int k = tid; k < KC; k += 256) {
    float p = (float)counts[k] * (1.0f / 16384.0f);
    ent += p * logf(p + 1e-10f);
  }
  for (int o = 32; o > 0; o >>= 1) ent += __shfl_down(ent, o);
  __shared__ float ps[4];
  if ((tid & 63) == 0) ps[tid >> 6] = ent;
  __syncthreads();
  if (tid == 0) {
    float total = (ps[0] + ps[1]) + (ps[2] + ps[3]);
    out[0] = 1.25f * loss_acc[0] * (1.0f / 8388608.0f);  // q + 0.25*e latent
    out[OUT_P_OFF] = expf(-total);
  }
}

extern "C" void kernel_launch(void* const* d_in, const int* in_sizes, int n_in,
                              void* d_out, int out_size, void* d_ws, size_t ws_size,
                              hipStream_t stream) {
  const float* x = (const float*)d_in[0];
  const float* W = (const float*)d_in[1];
  float* out = (float*)d_out;
  char* ws = (char*)d_ws;
  int*          counts   = (int*)(ws + WS_COUNTS);
  float*        loss_acc = (float*)(ws + WS_LOSS);
  double*       w2d      = (double*)(ws + WS_W2D);
  float*        w2f      = (float*)(ws + WS_W2F);
  signed char*  Wb       = (signed char*)(ws + WS_WB);

  k_prep<<<512, 256, 0, stream>>>(W, w2d, w2f, Wb, counts, loss_acc);
  k_main<<<NROWS / MB, 256, 0, stream>>>(x, W, Wb, w2f, w2d, counts, out, loss_acc);
  k_final<<<1, 256, 0, stream>>>(counts, loss_acc, out);
}